// Round 2
// baseline (1291.851 us; speedup 1.0000x reference)
//
#include <hip/hip_runtime.h>

#define D 64
#define BSHIFT 7   // rows per bucket = 128

// ---------------- layer-0 init: embs[node][0][:] = concat(user_emb, item_emb) ----
__global__ void init_emb_kernel(const float4* __restrict__ ue, const float4* __restrict__ ie,
                                float4* __restrict__ embs, int n_users, int n) {
    int idx  = blockIdx.x * blockDim.x + threadIdx.x;     // over n*16 float4s
    int node = idx >> 4, q = idx & 15;
    if (node >= n) return;
    float4 v = (node < n_users) ? ue[node * 16 + q] : ie[(node - n_users) * 16 + q];
    embs[(size_t)node * 64 + q] = v;                      // node stride = 256 floats = 64 float4
}

// ---------------- CSR build ------------------------------------------------------
__global__ void hist_kernel(const int* __restrict__ row, int* __restrict__ counts, int m) {
    int i = blockIdx.x * blockDim.x + threadIdx.x;
    if (i < m) atomicAdd(&counts[row[i]], 1);
}

__global__ void blocksum_kernel(const int* __restrict__ counts, int* __restrict__ bsum, int n) {
    __shared__ int s[256];
    int t = threadIdx.x;
    int i = blockIdx.x * 256 + t;
    s[t] = (i < n) ? counts[i] : 0;
    __syncthreads();
    for (int d = 128; d > 0; d >>= 1) {
        if (t < d) s[t] += s[t + d];
        __syncthreads();
    }
    if (t == 0) bsum[blockIdx.x] = s[0];
}

// single block, 1024 threads; nb <= 1024 (nb = ceil(150000/256) = 586)
__global__ void scanb_kernel(const int* __restrict__ bsum, int* __restrict__ boff, int nb) {
    __shared__ int s[1024];
    int t = threadIdx.x;
    int v = (t < nb) ? bsum[t] : 0;
    s[t] = v;
    for (int d = 1; d < 1024; d <<= 1) {
        __syncthreads();
        int add = (t >= d) ? s[t - d] : 0;
        __syncthreads();
        s[t] += add;
    }
    __syncthreads();
    if (t < nb) boff[t] = s[t] - v;   // exclusive
}

// in-place: counts -> exclusive offsets; also init per-row cursors
__global__ void final_kernel(int* __restrict__ offs, int* __restrict__ cursors,
                             const int* __restrict__ boff, int n, int total) {
    __shared__ int s[256];
    int t = threadIdx.x;
    int i = blockIdx.x * 256 + t;
    int v = (i < n) ? offs[i] : 0;
    s[t] = v;
    for (int d = 1; d < 256; d <<= 1) {
        __syncthreads();
        int add = (t >= d) ? s[t - d] : 0;
        __syncthreads();
        s[t] += add;
    }
    __syncthreads();
    int excl = s[t] - v + boff[blockIdx.x];
    if (i < n) { offs[i] = excl; cursors[i] = excl; }
    if (i == 0) offs[n] = total;
}

// ---------------- scatter path 1: legacy single-pass (ws fallback) ---------------
__global__ void scatter_kernel(const int* __restrict__ row, const int* __restrict__ col,
                               const float* __restrict__ val, int* __restrict__ cursors,
                               int2* __restrict__ edges, int m) {
    int i = blockIdx.x * blockDim.x + threadIdx.x;
    if (i >= m) return;
    int r   = row[i];
    int pos = atomicAdd(&cursors[r], 1);
    edges[pos] = make_int2(col[i], __float_as_int(val[i]));
}

// ---------------- scatter path 2: two-pass bucketed ------------------------------
// bucket b covers rows [b<<BSHIFT, (b+1)<<BSHIFT); its CSR segment starts at
// offs[b<<BSHIFT] -- cursor-monotonic writes keep lines fully dirtied in L2.
__global__ void bcur_init_kernel(const int* __restrict__ offs, int* __restrict__ bcur,
                                 int n, int nbk) {
    int b = blockIdx.x * blockDim.x + threadIdx.x;
    if (b >= nbk) return;
    int r = b << BSHIFT;
    bcur[b] = offs[r < n ? r : n];
}

__global__ void bucket_scatter_kernel(const int* __restrict__ row, const int* __restrict__ col,
                                      const float* __restrict__ val, int* __restrict__ bcur,
                                      int2* __restrict__ scv, int* __restrict__ srow, int m) {
    int i = blockIdx.x * blockDim.x + threadIdx.x;
    if (i >= m) return;
    int r   = row[i];
    int pos = atomicAdd(&bcur[r >> BSHIFT], 1);
    scv[pos]  = make_int2(col[i], __float_as_int(val[i]));
    srow[pos] = r;
}

__global__ void finalize_scatter_kernel(const int* __restrict__ srow, const int2* __restrict__ scv,
                                        int* __restrict__ cursors, int2* __restrict__ edges, int m) {
    int i = blockIdx.x * blockDim.x + threadIdx.x;
    if (i >= m) return;
    int r   = srow[i];
    int pos = atomicAdd(&cursors[r], 1);  // pos stays inside this bucket's ~20KB segment (L2-hot)
    edges[pos] = scv[i];
}

// ---------------- SpMM: one wave per row, 4 edges in flight ----------------------
// lane = 16*eg + c : 16-lane group eg gathers edge (j+eg)'s row as float4 chunks.
// x = embs + (l-1)*64 (node stride 256 floats), y = embs + l*64
__global__ void __launch_bounds__(256) spmm_kernel(const int* __restrict__ offs,
                                                   const int2* __restrict__ edges,
                                                   const float* __restrict__ x,
                                                   float* __restrict__ y, int n) {
    int wid  = (int)((blockIdx.x * (size_t)blockDim.x + threadIdx.x) >> 6);
    if (wid >= n) return;
    int lane = threadIdx.x & 63;
    int eg   = lane >> 4;      // which of 4 concurrent edges
    int c    = lane & 15;      // float4 chunk within the 64-dim row
    int beg = offs[wid], end = offs[wid + 1];
    float4 acc = make_float4(0.f, 0.f, 0.f, 0.f);
    int nfull = (end - beg) & ~3;
    int j = beg;
#pragma unroll 2
    for (; j < beg + nfull; j += 4) {           // 4 (x2 unrolled = 8) gathers in flight
        int2 e = edges[j + eg];
        float v = __int_as_float(e.y);
        float4 xv = ((const float4*)(x + (size_t)e.x * 256))[c];
        acc.x += v * xv.x; acc.y += v * xv.y; acc.z += v * xv.z; acc.w += v * xv.w;
    }
    if (j + eg < end) {
        int2 e = edges[j + eg];
        float v = __int_as_float(e.y);
        float4 xv = ((const float4*)(x + (size_t)e.x * 256))[c];
        acc.x += v * xv.x; acc.y += v * xv.y; acc.z += v * xv.z; acc.w += v * xv.w;
    }
    // reduce the 4 edge-groups: butterfly over lane bits 4,5
    acc.x += __shfl_xor(acc.x, 16); acc.y += __shfl_xor(acc.y, 16);
    acc.z += __shfl_xor(acc.z, 16); acc.w += __shfl_xor(acc.w, 16);
    acc.x += __shfl_xor(acc.x, 32); acc.y += __shfl_xor(acc.y, 32);
    acc.z += __shfl_xor(acc.z, 32); acc.w += __shfl_xor(acc.w, 32);
    if (eg == 0)
        ((float4*)(y + (size_t)wid * 256))[c] = acc;
}

// ---------------- mean over 4 layers -> users / items ----------------------------
__global__ void mean_kernel(const float4* __restrict__ embs, float4* __restrict__ users,
                            float4* __restrict__ items, int n_users, int n) {
    int idx  = blockIdx.x * blockDim.x + threadIdx.x;     // over n*16 float4s
    int node = idx >> 4, q = idx & 15;
    if (node >= n) return;
    const float4* p = embs + (size_t)node * 64 + q;
    float4 a = p[0], b = p[16], c = p[32], d = p[48];
    float4 mv;
    mv.x = (a.x + b.x + c.x + d.x) * 0.25f;
    mv.y = (a.y + b.y + c.y + d.y) * 0.25f;
    mv.z = (a.z + b.z + c.z + d.z) * 0.25f;
    mv.w = (a.w + b.w + c.w + d.w) * 0.25f;
    if (node < n_users) users[node * 16 + q] = mv;
    else                items[(node - n_users) * 16 + q] = mv;
}

extern "C" void kernel_launch(void* const* d_in, const int* in_sizes, int n_in,
                              void* d_out, int out_size, void* d_ws, size_t ws_size,
                              hipStream_t stream) {
    const float* user_emb = (const float*)d_in[0];
    const float* item_emb = (const float*)d_in[1];
    const int*   edge_row = (const int*)d_in[2];
    const int*   edge_col = (const int*)d_in[3];
    const float* edge_val = (const float*)d_in[4];

    const int n_users = in_sizes[0] / D;
    const int n_items = in_sizes[1] / D;
    const int n       = n_users + n_items;
    const int m       = in_sizes[2];

    float* out_users = (float*)d_out;                       // (n_users, 64)
    float* out_items = out_users + (size_t)n_users * D;     // (n_items, 64)
    float* embs      = out_items + (size_t)n_items * D;     // (n, 4, 64)

    // workspace carve-up
    char* ws = (char*)d_ws;
    int*  offs    = (int*)ws;                // n+1 (counts -> offsets, in place)
    int*  cursors = offs + (n + 1);          // n
    const int nb  = (n + 255) / 256;         // 586 (must be <= 1024 for scanb)
    const int nbk = (n + (1 << BSHIFT) - 1) >> BSHIFT;   // buckets (1172)
    int*  bsum    = cursors + n;             // nb
    int*  boff    = bsum + nb;               // nb
    int*  bcur    = boff + nb;               // nbk
    size_t int_bytes = ((size_t)(n + 1) + n + nb + nb + nbk) * sizeof(int);
    size_t edge_off  = (int_bytes + 15) & ~(size_t)15;
    int2* cedges = (int2*)(ws + edge_off);   // m pairs (col, val), row-segment order
    size_t staged_off = edge_off + (size_t)m * sizeof(int2);
    int2* scv  = (int2*)(ws + staged_off);   // m pairs, bucket order
    int*  srow = (int*)(ws + staged_off + (size_t)m * sizeof(int2));  // m rows, bucket order
    size_t need_2pass = staged_off + (size_t)m * (sizeof(int2) + sizeof(int));
    const bool two_pass = (ws_size >= need_2pass);

    // 1. zero counts
    hipMemsetAsync(offs, 0, (size_t)n * sizeof(int), stream);

    // 2. layer-0 embeddings straight into d_out's embs region
    init_emb_kernel<<<(n * 16 + 255) / 256, 256, 0, stream>>>(
        (const float4*)user_emb, (const float4*)item_emb, (float4*)embs, n_users, n);

    // 3. CSR build
    hist_kernel<<<(m + 255) / 256, 256, 0, stream>>>(edge_row, offs, m);
    blocksum_kernel<<<nb, 256, 0, stream>>>(offs, bsum, n);
    scanb_kernel<<<1, 1024, 0, stream>>>(bsum, boff, nb);
    final_kernel<<<nb, 256, 0, stream>>>(offs, cursors, boff, n, m);

    if (two_pass) {
        bcur_init_kernel<<<(nbk + 255) / 256, 256, 0, stream>>>(offs, bcur, n, nbk);
        bucket_scatter_kernel<<<(m + 255) / 256, 256, 0, stream>>>(
            edge_row, edge_col, edge_val, bcur, scv, srow, m);
        finalize_scatter_kernel<<<(m + 255) / 256, 256, 0, stream>>>(
            srow, scv, cursors, cedges, m);
    } else {
        scatter_kernel<<<(m + 255) / 256, 256, 0, stream>>>(
            edge_row, edge_col, edge_val, cursors, cedges, m);
    }

    // 4. three propagation layers (gather-SpMM, no fp32 atomics)
    for (int l = 1; l <= 3; ++l) {
        spmm_kernel<<<(n + 3) / 4, 256, 0, stream>>>(offs, cedges,
                                                     embs + (size_t)(l - 1) * D,
                                                     embs + (size_t)l * D, n);
    }

    // 5. layer mean -> users / items
    mean_kernel<<<(n * 16 + 255) / 256, 256, 0, stream>>>(
        (const float4*)embs, (float4*)out_users, (float4*)out_items, n_users, n);
}

// Round 3
// 871.160 us; speedup vs baseline: 1.4829x; 1.4829x over previous
//
#include <hip/hip_runtime.h>

#define D 64
#define TILE 4096          // edges per radix tile (256 threads x 16)
#define BKSHIFT 10         // rows per coarse bucket = 1024

// ---------------- layer-0 init: embs[node][0][:] = concat(user_emb, item_emb) ----
__global__ void init_emb_kernel(const float4* __restrict__ ue, const float4* __restrict__ ie,
                                float4* __restrict__ embs, int n_users, int n) {
    int idx  = blockIdx.x * blockDim.x + threadIdx.x;     // over n*16 float4s
    int node = idx >> 4, q = idx & 15;
    if (node >= n) return;
    float4 v = (node < n_users) ? ue[node * 16 + q] : ie[(node - n_users) * 16 + q];
    embs[(size_t)node * 64 + q] = v;                      // node stride = 256 floats = 64 float4
}

// ================= radix CSR build (no global atomics) ===========================
// passA: per-tile histogram over coarse buckets -> hm[b*ntiles + t]
__global__ void passA_kernel(const int* __restrict__ row, int* __restrict__ hm,
                             int m, int ntiles, int nbk) {
    __shared__ int h[256];
    int t = threadIdx.x;
    h[t] = 0;
    __syncthreads();
    int base = blockIdx.x * TILE;
    for (int k = 0; k < TILE; k += 256) {
        int i = base + k + t;
        if (i < m) atomicAdd(&h[row[i] >> BKSHIFT], 1);
    }
    __syncthreads();
    if (t < nbk) hm[t * ntiles + blockIdx.x] = h[t];
}

// passB: single-block exclusive scan of hm (bucket-major) -> absolute edge offsets.
// Also emits bstart[b] (bucket segment starts) and offs[n] = m.
__global__ void __launch_bounds__(1024) passB_kernel(int* __restrict__ hm,
                                                     int* __restrict__ bstart,
                                                     int* __restrict__ offs_n,
                                                     int total, int len, int ntiles, int nbk) {
    __shared__ int s[1024];
    int t = threadIdx.x;
    int chunk = (len + 1023) / 1024;
    int beg = t * chunk;
    int end = beg + chunk; if (end > len) end = len; if (beg > len) beg = len;
    int sum = 0;
    for (int i = beg; i < end; ++i) sum += hm[i];
    s[t] = sum;
    for (int d = 1; d < 1024; d <<= 1) {
        __syncthreads();
        int add = (t >= d) ? s[t - d] : 0;
        __syncthreads();
        s[t] += add;
    }
    __syncthreads();
    int run = s[t] - sum;                  // exclusive prefix of this chunk
    for (int i = beg; i < end; ++i) {
        int v = hm[i];
        hm[i] = run;
        if (i % ntiles == 0) bstart[i / ntiles] = run;
        run += v;
    }
    if (t == 0) { bstart[nbk] = total; offs_n[0] = total; }
}

// passC: place edges into bucket-major staging. LDS cursors seeded from hm; each
// (tile,bucket) run (~28 edges) is contiguous and written by one block/XCD.
__global__ void passC_kernel(const int* __restrict__ row, const int* __restrict__ col,
                             const float* __restrict__ val, const int* __restrict__ hm,
                             int* __restrict__ brow, int2* __restrict__ bcv,
                             int m, int ntiles, int nbk) {
    __shared__ int cur[256];
    int t = threadIdx.x;
    if (t < nbk) cur[t] = hm[t * ntiles + blockIdx.x];
    __syncthreads();
    int base = blockIdx.x * TILE;
    for (int k = 0; k < TILE; k += 256) {
        int i = base + k + t;
        if (i < m) {
            int r = row[i];
            int dst = atomicAdd(&cur[r >> BKSHIFT], 1);
            brow[dst] = r;
            bcv[dst]  = make_int2(col[i], __float_as_int(val[i]));
        }
    }
}

// pass2: one block per bucket. LDS row-hist + scan -> row CSR offs (coalesced write),
// then exact placement; all scattered writes stay in this bucket's segment (one XCD).
__global__ void __launch_bounds__(1024) pass2_kernel(const int* __restrict__ brow,
                                                     const int2* __restrict__ bcv,
                                                     const int* __restrict__ bstart,
                                                     int* __restrict__ offs,
                                                     int2* __restrict__ cedges, int n) {
    __shared__ int hist[1024];
    __shared__ int s[1024];
    int b = blockIdx.x;
    int t = threadIdx.x;
    int e0 = bstart[b], e1 = bstart[b + 1];
    hist[t] = 0;
    __syncthreads();
    for (int i = e0 + t; i < e1; i += 1024)
        atomicAdd(&hist[brow[i] & ((1 << BKSHIFT) - 1)], 1);
    __syncthreads();
    int v = hist[t];
    s[t] = v;
    for (int d = 1; d < 1024; d <<= 1) {
        __syncthreads();
        int add = (t >= d) ? s[t - d] : 0;
        __syncthreads();
        s[t] += add;
    }
    __syncthreads();
    int abs_off = e0 + s[t] - v;           // absolute CSR start of this row
    int grow = (b << BKSHIFT) + t;
    if (grow < n) offs[grow] = abs_off;
    __syncthreads();
    hist[t] = abs_off;                     // reuse as absolute cursor
    __syncthreads();
    for (int i = e0 + t; i < e1; i += 1024) {
        int r = brow[i];
        int pos = atomicAdd(&hist[r & ((1 << BKSHIFT) - 1)], 1);
        cedges[pos] = bcv[i];
    }
}

// ================= legacy fallback (ws too small): hist chain + 1-pass scatter ===
__global__ void hist_kernel(const int* __restrict__ row, int* __restrict__ counts, int m) {
    int i = blockIdx.x * blockDim.x + threadIdx.x;
    if (i < m) atomicAdd(&counts[row[i]], 1);
}
__global__ void blocksum_kernel(const int* __restrict__ counts, int* __restrict__ bsum, int n) {
    __shared__ int s[256];
    int t = threadIdx.x;
    int i = blockIdx.x * 256 + t;
    s[t] = (i < n) ? counts[i] : 0;
    __syncthreads();
    for (int d = 128; d > 0; d >>= 1) {
        if (t < d) s[t] += s[t + d];
        __syncthreads();
    }
    if (t == 0) bsum[blockIdx.x] = s[0];
}
__global__ void scanb_kernel(const int* __restrict__ bsum, int* __restrict__ boff, int nb) {
    __shared__ int s[1024];
    int t = threadIdx.x;
    int v = (t < nb) ? bsum[t] : 0;
    s[t] = v;
    for (int d = 1; d < 1024; d <<= 1) {
        __syncthreads();
        int add = (t >= d) ? s[t - d] : 0;
        __syncthreads();
        s[t] += add;
    }
    __syncthreads();
    if (t < nb) boff[t] = s[t] - v;
}
__global__ void final_kernel(int* __restrict__ offs, int* __restrict__ cursors,
                             const int* __restrict__ boff, int n, int total) {
    __shared__ int s[256];
    int t = threadIdx.x;
    int i = blockIdx.x * 256 + t;
    int v = (i < n) ? offs[i] : 0;
    s[t] = v;
    for (int d = 1; d < 256; d <<= 1) {
        __syncthreads();
        int add = (t >= d) ? s[t - d] : 0;
        __syncthreads();
        s[t] += add;
    }
    __syncthreads();
    int excl = s[t] - v + boff[blockIdx.x];
    if (i < n) { offs[i] = excl; cursors[i] = excl; }
    if (i == 0) offs[n] = total;
}
__global__ void scatter_kernel(const int* __restrict__ row, const int* __restrict__ col,
                               const float* __restrict__ val, int* __restrict__ cursors,
                               int2* __restrict__ edges, int m) {
    int i = blockIdx.x * blockDim.x + threadIdx.x;
    if (i >= m) return;
    int r   = row[i];
    int pos = atomicAdd(&cursors[r], 1);
    edges[pos] = make_int2(col[i], __float_as_int(val[i]));
}

// ---------------- SpMM: one wave per row, 4 edges in flight ----------------------
__global__ void __launch_bounds__(256) spmm_kernel(const int* __restrict__ offs,
                                                   const int2* __restrict__ edges,
                                                   const float* __restrict__ x,
                                                   float* __restrict__ y, int n) {
    int wid  = (int)((blockIdx.x * (size_t)blockDim.x + threadIdx.x) >> 6);
    if (wid >= n) return;
    int lane = threadIdx.x & 63;
    int eg   = lane >> 4;      // which of 4 concurrent edges
    int c    = lane & 15;      // float4 chunk within the 64-dim row
    int beg = offs[wid], end = offs[wid + 1];
    float4 acc = make_float4(0.f, 0.f, 0.f, 0.f);
    int nfull = (end - beg) & ~3;
    int j = beg;
#pragma unroll 2
    for (; j < beg + nfull; j += 4) {
        int2 e = edges[j + eg];
        float v = __int_as_float(e.y);
        float4 xv = ((const float4*)(x + (size_t)e.x * 256))[c];
        acc.x += v * xv.x; acc.y += v * xv.y; acc.z += v * xv.z; acc.w += v * xv.w;
    }
    if (j + eg < end) {
        int2 e = edges[j + eg];
        float v = __int_as_float(e.y);
        float4 xv = ((const float4*)(x + (size_t)e.x * 256))[c];
        acc.x += v * xv.x; acc.y += v * xv.y; acc.z += v * xv.z; acc.w += v * xv.w;
    }
    acc.x += __shfl_xor(acc.x, 16); acc.y += __shfl_xor(acc.y, 16);
    acc.z += __shfl_xor(acc.z, 16); acc.w += __shfl_xor(acc.w, 16);
    acc.x += __shfl_xor(acc.x, 32); acc.y += __shfl_xor(acc.y, 32);
    acc.z += __shfl_xor(acc.z, 32); acc.w += __shfl_xor(acc.w, 32);
    if (eg == 0)
        ((float4*)(y + (size_t)wid * 256))[c] = acc;
}

// ---------------- mean over 4 layers -> users / items ----------------------------
__global__ void mean_kernel(const float4* __restrict__ embs, float4* __restrict__ users,
                            float4* __restrict__ items, int n_users, int n) {
    int idx  = blockIdx.x * blockDim.x + threadIdx.x;
    int node = idx >> 4, q = idx & 15;
    if (node >= n) return;
    const float4* p = embs + (size_t)node * 64 + q;
    float4 a = p[0], b = p[16], c = p[32], d = p[48];
    float4 mv;
    mv.x = (a.x + b.x + c.x + d.x) * 0.25f;
    mv.y = (a.y + b.y + c.y + d.y) * 0.25f;
    mv.z = (a.z + b.z + c.z + d.z) * 0.25f;
    mv.w = (a.w + b.w + c.w + d.w) * 0.25f;
    if (node < n_users) users[node * 16 + q] = mv;
    else                items[(node - n_users) * 16 + q] = mv;
}

extern "C" void kernel_launch(void* const* d_in, const int* in_sizes, int n_in,
                              void* d_out, int out_size, void* d_ws, size_t ws_size,
                              hipStream_t stream) {
    const float* user_emb = (const float*)d_in[0];
    const float* item_emb = (const float*)d_in[1];
    const int*   edge_row = (const int*)d_in[2];
    const int*   edge_col = (const int*)d_in[3];
    const float* edge_val = (const float*)d_in[4];

    const int n_users = in_sizes[0] / D;
    const int n_items = in_sizes[1] / D;
    const int n       = n_users + n_items;
    const int m       = in_sizes[2];

    float* out_users = (float*)d_out;                       // (n_users, 64)
    float* out_items = out_users + (size_t)n_users * D;     // (n_items, 64)
    float* embs      = out_items + (size_t)n_items * D;     // (n, 4, 64)

    const int ntiles = (m + TILE - 1) / TILE;               // 733
    const int nbk    = (n + (1 << BKSHIFT) - 1) >> BKSHIFT; // 147 (must be <= 256)
    const int nb     = (n + 255) / 256;                     // 586 (fallback scan)

    // workspace carve-up (8-byte aligned pieces first)
    char* ws = (char*)d_ws;
    size_t off = 0;
    int2* cedges = (int2*)(ws + off); off += (size_t)m * sizeof(int2);
    int2* bcv    = (int2*)(ws + off); off += (size_t)m * sizeof(int2);
    int*  brow   = (int*)(ws + off);  off += (size_t)m * sizeof(int);
    int*  offs   = (int*)(ws + off);  off += (size_t)(n + 1) * sizeof(int);
    int*  bstart = (int*)(ws + off);  off += (size_t)(nbk + 1) * sizeof(int);
    int*  hm     = (int*)(ws + off);  off += (size_t)nbk * ntiles * sizeof(int);
    int*  cursors= (int*)(ws + off);  off += (size_t)n * sizeof(int);
    int*  bsum   = (int*)(ws + off);  off += (size_t)nb * sizeof(int);
    int*  boff   = (int*)(ws + off);  off += (size_t)nb * sizeof(int);
    const bool radix = (ws_size >= off);

    // layer-0 embeddings straight into d_out's embs region
    init_emb_kernel<<<(n * 16 + 255) / 256, 256, 0, stream>>>(
        (const float4*)user_emb, (const float4*)item_emb, (float4*)embs, n_users, n);

    if (radix) {
        // deterministic two-level radix CSR build, no global atomics
        passA_kernel<<<ntiles, 256, 0, stream>>>(edge_row, hm, m, ntiles, nbk);
        passB_kernel<<<1, 1024, 0, stream>>>(hm, bstart, offs + n, m,
                                             nbk * ntiles, ntiles, nbk);
        passC_kernel<<<ntiles, 256, 0, stream>>>(edge_row, edge_col, edge_val, hm,
                                                 brow, bcv, m, ntiles, nbk);
        pass2_kernel<<<nbk, 1024, 0, stream>>>(brow, bcv, bstart, offs, cedges, n);
    } else {
        hipMemsetAsync(offs, 0, (size_t)n * sizeof(int), stream);
        hist_kernel<<<(m + 255) / 256, 256, 0, stream>>>(edge_row, offs, m);
        blocksum_kernel<<<nb, 256, 0, stream>>>(offs, bsum, n);
        scanb_kernel<<<1, 1024, 0, stream>>>(bsum, boff, nb);
        final_kernel<<<nb, 256, 0, stream>>>(offs, cursors, boff, n, m);
        scatter_kernel<<<(m + 255) / 256, 256, 0, stream>>>(
            edge_row, edge_col, edge_val, cursors, cedges, m);
    }

    // three propagation layers (gather-SpMM, no fp32 atomics)
    for (int l = 1; l <= 3; ++l) {
        spmm_kernel<<<(n + 3) / 4, 256, 0, stream>>>(offs, cedges,
                                                     embs + (size_t)(l - 1) * D,
                                                     embs + (size_t)l * D, n);
    }

    // layer mean -> users / items
    mean_kernel<<<(n * 16 + 255) / 256, 256, 0, stream>>>(
        (const float4*)embs, (float4*)out_users, (float4*)out_items, n_users, n);
}